// Round 3
// baseline (287.222 us; speedup 1.0000x reference)
//
#include <hip/hip_runtime.h>
#include <math.h>

#define PP   7
#define NDIR 49
#define CIN  3
#define KK   147      // CIN * 49
#define EE   384
#define HH   224
#define WW   224
#define GG   16       // patches per block
#define TB   384      // threads per block

typedef __attribute__((ext_vector_type(8))) __bf16 bf16x8;
typedef __attribute__((ext_vector_type(4))) float  f32x4;

__device__ __forceinline__ float sigmoidf_(float v) {
    return 1.0f / (1.0f + expf(-v));
}

__launch_bounds__(TB)
__global__ void metric_patch_kernel(const float* __restrict__ x,
                                    const float* __restrict__ mw,
                                    const float* __restrict__ mb,
                                    const float* __restrict__ pw,
                                    const float* __restrict__ pb,
                                    float* __restrict__ out) {
    __shared__ float strip[21][112];                 // x patch strip: [c*7+i][col]
    __shared__ float mws[7 * KK];                    // metric_w [o][k]
    __shared__ float params_s[GG][8];
    __shared__ float der[GG][8];                     // M00,M01,M11,w0,w1
    __shared__ float samp[KK][GG];                   // sampled fp32, k-major (PROVEN R1 layout)

    const int t   = threadIdx.x;
    const int blk = blockIdx.x;
    const int b   = blk >> 6;          // 64 blocks per image
    const int rem = blk & 63;
    const int hp  = rem >> 1;
    const int wp0 = (rem & 1) * GG;

    const float* xb = x + (size_t)b * (CIN * HH * WW);

    // ---- stage x strip (21 rows x 112 cols, coalesced) + metric_w
    for (int idx = t; idx < 21 * 112; idx += TB) {
        int r = idx / 112;
        int col = idx - r * 112;
        int c = r / 7;
        int i = r - c * 7;
        strip[r][col] = xb[c * (HH * WW) + (hp * PP + i) * WW + wp0 * PP + col];
    }
    for (int idx = t; idx < 7 * KK; idx += TB) {
        mws[idx] = mw[idx];
    }
    __syncthreads();

    // ---- metric conv: params[g][o]
    if (t < GG * 7) {
        int g = t / 7;
        int o = t - g * 7;
        float acc = mb[o];
        const float* wrow = &mws[o * KK];
        int k = 0;
        for (int c = 0; c < CIN; ++c)
            for (int i = 0; i < PP; ++i) {
                const float* srow = &strip[c * PP + i][g * PP];
                #pragma unroll
                for (int j = 0; j < PP; ++j, ++k)
                    acc = fmaf(srow[j], wrow[k], acc);
            }
        params_s[g][o] = acc;
    }
    __syncthreads();

    // ---- derived per-patch quantities
    if (t < GG) {
        float p0 = params_s[t][0], p1 = params_s[t][1];
        float p2 = params_s[t][2], p3 = params_s[t][3];
        float p4 = params_s[t][4];
        float p5 = params_s[t][5], p6 = params_s[t][6];
        float nrm = sqrtf(p0 * p0 + p1 * p1);
        float inv = 1.0f / fmaxf(nrm, 1e-12f);
        float v0 = p0 * inv, v1 = p1 * inv;
        float e0 = 2.0f * sigmoidf_(p2);
        float e1 = 2.0f * sigmoidf_(p3);
        float sc = 0.5f + 1.5f * sigmoidf_(p4);
        e0 *= sc; e1 *= sc;
        der[t][0] = e0 * v0 * v0 + e1 * v1 * v1;     // M00
        der[t][1] = (e0 - e1) * v0 * v1;             // M01
        der[t][2] = e0 * v1 * v1 + e1 * v0 * v0;     // M11
        float wn  = sqrtf(p5 * p5 + p6 * p6);
        float wsc = 0.5f * sigmoidf_(wn);
        der[t][3] = p5 * wsc;                        // w0
        der[t][4] = p6 * wsc;                        // w1
    }
    __syncthreads();

    // ---- positions + bilinear gather into samp[k][g]  (PROVEN R1 code, fp32)
    for (int item = t; item < GG * NDIR; item += TB) {
        int g = item / NDIR;
        int n = item - g * NDIR;
        float u0, u1, s;
        if (n == 0)      { u0 = 1.0f; u1 = 0.0f; s = 0.0f; }
        else if (n < 9)  { float th = (float)(n - 1)  * 0.78539816339744831f; u0 = cosf(th); u1 = sinf(th); s = 0.33333334f; }
        else if (n < 25) { float th = (float)(n - 9)  * 0.39269908169872414f; u0 = cosf(th); u1 = sinf(th); s = 0.66666669f; }
        else             { float th = (float)(n - 25) * 0.26179938779914941f; u0 = cosf(th); u1 = sinf(th); s = 1.0f; }
        float M00 = der[g][0], M01 = der[g][1], M11 = der[g][2];
        float w0 = der[g][3], w1 = der[g][4];
        float quad  = u0 * u0 * M00 + 2.0f * u0 * u1 * M01 + u1 * u1 * M11;
        float drift = w0 * u0 + w1 * u1;
        float F = sqrtf(quad + 1e-6f) + drift;
        float r = s / (F + 1e-6f);
        float py = (float)(hp * PP + 3) + u1 * r;
        float px = (float)((wp0 + g) * PP + 3) + u0 * r;
        float y0f = floorf(py), x0f = floorf(px);
        float y1f = y0f + 1.0f, x1f = x0f + 1.0f;
        float wy = py - y0f, wx = px - x0f;
        bool vy0 = (y0f >= 0.0f) && (y0f <= (float)(HH - 1));
        bool vy1 = (y1f >= 0.0f) && (y1f <= (float)(HH - 1));
        bool vx0 = (x0f >= 0.0f) && (x0f <= (float)(WW - 1));
        bool vx1 = (x1f >= 0.0f) && (x1f <= (float)(WW - 1));
        int iy0 = (int)fminf(fmaxf(y0f, 0.0f), (float)(HH - 1));
        int iy1 = (int)fminf(fmaxf(y1f, 0.0f), (float)(HH - 1));
        int ix0 = (int)fminf(fmaxf(x0f, 0.0f), (float)(WW - 1));
        int ix1 = (int)fminf(fmaxf(x1f, 0.0f), (float)(WW - 1));
        float w00 = (1.0f - wy) * (1.0f - wx);
        float w01 = (1.0f - wy) * wx;
        float w10 = wy * (1.0f - wx);
        float w11 = wy * wx;
        #pragma unroll
        for (int c = 0; c < CIN; ++c) {
            const float* xc = xb + c * (HH * WW);
            float v00 = (vy0 && vx0) ? xc[iy0 * WW + ix0] : 0.0f;
            float v01 = (vy0 && vx1) ? xc[iy0 * WW + ix1] : 0.0f;
            float v10 = (vy1 && vx0) ? xc[iy1 * WW + ix0] : 0.0f;
            float v11 = (vy1 && vx1) ? xc[iy1 * WW + ix1] : 0.0f;
            samp[c * NDIR + n][g] = v00 * w00 + v01 * w01 + v10 * w10 + v11 * w11;
        }
    }
    __syncthreads();

    // ---- projection GEMM via MFMA bf16 16x16x32, fragments built IN-REGISTER
    // from the proven fp32 samp[k][g] LDS array and pw directly from global.
    const int lane = t & 63;
    const int wv   = t >> 6;           // 0..5
    const int nrow = lane & 15;        // A row m / B col n / D col
    const int hi   = lane >> 4;        // k-quad / D row quad
    const size_t m0 = (size_t)blk * GG;

    // A fragments (5 k-steps of 32), k = ks*32 + hi*8 + j, mask k >= 147 to 0
    bf16x8 afr[5];
    #pragma unroll
    for (int ks = 0; ks < 5; ++ks) {
        #pragma unroll
        for (int j = 0; j < 8; ++j) {
            int k = ks * 32 + hi * 8 + j;
            float v = (k < KK) ? samp[k][nrow] : 0.0f;
            afr[ks][j] = (__bf16)v;
        }
    }

    #pragma unroll
    for (int q = 0; q < 4; ++q) {
        int tile = wv * 4 + q;
        int e    = tile * 16 + nrow;
        const float* prow = pw + (size_t)e * KK;
        f32x4 acc = {0.0f, 0.0f, 0.0f, 0.0f};
        #pragma unroll
        for (int ks = 0; ks < 5; ++ks) {
            bf16x8 bfr;
            #pragma unroll
            for (int j = 0; j < 8; ++j) {
                int k = ks * 32 + hi * 8 + j;
                float v = (k < KK) ? prow[k] : 0.0f;
                bfr[j] = (__bf16)v;
            }
            acc = __builtin_amdgcn_mfma_f32_16x16x32_bf16(afr[ks], bfr, acc, 0, 0, 0);
        }
        float bias = pb[e];
        #pragma unroll
        for (int r = 0; r < 4; ++r) {
            out[(m0 + hi * 4 + r) * EE + e] = acc[r] + bias;
        }
    }
}

extern "C" void kernel_launch(void* const* d_in, const int* in_sizes, int n_in,
                              void* d_out, int out_size, void* d_ws, size_t ws_size,
                              hipStream_t stream) {
    const float* x  = (const float*)d_in[0];
    const float* mw = (const float*)d_in[1];
    const float* mb = (const float*)d_in[2];
    const float* pw = (const float*)d_in[3];
    const float* pb = (const float*)d_in[4];
    float* out = (float*)d_out;

    const int B = in_sizes[0] / (CIN * HH * WW);   // 64

    metric_patch_kernel<<<B * 64, TB, 0, stream>>>(x, mw, mb, pw, pb, out);
}

// Round 4
// 258.863 us; speedup vs baseline: 1.1096x; 1.1096x over previous
//
#include <hip/hip_runtime.h>
#include <math.h>

#define PP   7
#define NDIR 49
#define CIN  3
#define KK   147      // CIN * 49
#define EE   384
#define HH   224
#define WW   224
#define GG   16       // patches per block (main kernel)
#define TB1  256
#define TB2  256
#define SSTR 17       // samp LDS row stride (+1 pad: conflict-free A reads)

typedef __attribute__((ext_vector_type(8))) __bf16 bf16x8;
typedef __attribute__((ext_vector_type(4))) float  f32x4;

__device__ __forceinline__ float sigmoidf_(float v) {
    return 1.0f / (1.0f + expf(-v));
}

// ---- K1: per-patch metric conv + derived quantities -> der[p*8 + {0..4}]
// one thread per patch; weights staged in LDS; x read coalesced-ish (L3-hot)
__launch_bounds__(TB1)
__global__ void params_kernel(const float* __restrict__ x,
                              const float* __restrict__ mw,
                              const float* __restrict__ mb,
                              float* __restrict__ der) {
    __shared__ float mws[7 * KK];
    const int t = threadIdx.x;
    for (int i = t; i < 7 * KK; i += TB1) mws[i] = mw[i];
    __syncthreads();

    const int p   = blockIdx.x * TB1 + t;     // 0..65535
    const int b   = p >> 10;
    const int rem = p & 1023;
    const int hp  = rem >> 5;
    const int wp  = rem & 31;
    const float* xb = x + (size_t)b * (CIN * HH * WW) + (size_t)(hp * PP) * WW + wp * PP;

    float a0 = mb[0], a1 = mb[1], a2 = mb[2], a3 = mb[3], a4 = mb[4], a5 = mb[5], a6 = mb[6];
    #pragma unroll
    for (int c = 0; c < CIN; ++c) {
        #pragma unroll
        for (int i = 0; i < PP; ++i) {
            const float* row = xb + c * (HH * WW) + i * WW;
            float v[7];
            #pragma unroll
            for (int j = 0; j < PP; ++j) v[j] = row[j];
            const int kb = c * 49 + i * 7;
            #pragma unroll
            for (int j = 0; j < PP; ++j) {
                a0 = fmaf(v[j], mws[0 * KK + kb + j], a0);
                a1 = fmaf(v[j], mws[1 * KK + kb + j], a1);
                a2 = fmaf(v[j], mws[2 * KK + kb + j], a2);
                a3 = fmaf(v[j], mws[3 * KK + kb + j], a3);
                a4 = fmaf(v[j], mws[4 * KK + kb + j], a4);
                a5 = fmaf(v[j], mws[5 * KK + kb + j], a5);
                a6 = fmaf(v[j], mws[6 * KK + kb + j], a6);
            }
        }
    }

    // derived (identical math to proven R3)
    float nrm = sqrtf(a0 * a0 + a1 * a1);
    float inv = 1.0f / fmaxf(nrm, 1e-12f);
    float v0 = a0 * inv, v1 = a1 * inv;
    float e0 = 2.0f * sigmoidf_(a2);
    float e1 = 2.0f * sigmoidf_(a3);
    float sc = 0.5f + 1.5f * sigmoidf_(a4);
    e0 *= sc; e1 *= sc;
    float M00 = e0 * v0 * v0 + e1 * v1 * v1;
    float M01 = (e0 - e1) * v0 * v1;
    float M11 = e0 * v1 * v1 + e1 * v0 * v0;
    float wn  = sqrtf(a5 * a5 + a6 * a6);
    float wsc = 0.5f * sigmoidf_(wn);

    float* dp = der + (size_t)p * 8;
    dp[0] = M00; dp[1] = M01; dp[2] = M11; dp[3] = a5 * wsc; dp[4] = a6 * wsc;
}

// ---- K2: gather + MFMA projection GEMM. 256 threads (4 waves), 16 patches.
__launch_bounds__(TB2)
__global__ void gather_gemm_kernel(const float* __restrict__ x,
                                   const float* __restrict__ derg,
                                   const float* __restrict__ pw,
                                   const float* __restrict__ pb,
                                   float* __restrict__ out) {
    __shared__ float der_s[GG][5];
    __shared__ float dirs[NDIR][3];
    __shared__ float samp[KK][SSTR];   // fp32, row stride 17

    const int t   = threadIdx.x;
    const int blk = blockIdx.x;
    const int b   = blk >> 6;
    const int rem = blk & 63;
    const int hp  = rem >> 1;
    const int wp0 = (rem & 1) * GG;
    const size_t m0 = (size_t)blk * GG;

    const float* xb = x + (size_t)b * (CIN * HH * WW);

    // ---- init: derived params + direction table
    if (t < GG * 5) {
        int g = t / 5, f = t - g * 5;
        der_s[g][f] = derg[(m0 + g) * 8 + f];
    }
    if (t >= 64 && t < 64 + NDIR) {
        int n = t - 64;
        float u0, u1, s;
        if (n == 0)      { u0 = 1.0f; u1 = 0.0f; s = 0.0f; }
        else if (n < 9)  { float th = (float)(n - 1)  * 0.78539816339744831f; u0 = cosf(th); u1 = sinf(th); s = 0.33333334f; }
        else if (n < 25) { float th = (float)(n - 9)  * 0.39269908169872414f; u0 = cosf(th); u1 = sinf(th); s = 0.66666669f; }
        else             { float th = (float)(n - 25) * 0.26179938779914941f; u0 = cosf(th); u1 = sinf(th); s = 1.0f; }
        dirs[n][0] = u0; dirs[n][1] = u1; dirs[n][2] = s;
    }
    __syncthreads();

    // ---- positions + bilinear gather into samp[k][g] (proven R3 math)
    for (int item = t; item < GG * NDIR; item += TB2) {
        int g = item / NDIR;
        int n = item - g * NDIR;
        float u0 = dirs[n][0], u1 = dirs[n][1], s = dirs[n][2];
        float M00 = der_s[g][0], M01 = der_s[g][1], M11 = der_s[g][2];
        float w0 = der_s[g][3], w1 = der_s[g][4];
        float quad  = u0 * u0 * M00 + 2.0f * u0 * u1 * M01 + u1 * u1 * M11;
        float drift = w0 * u0 + w1 * u1;
        float F = sqrtf(quad + 1e-6f) + drift;
        float r = s / (F + 1e-6f);
        float py = (float)(hp * PP + 3) + u1 * r;
        float px = (float)((wp0 + g) * PP + 3) + u0 * r;
        float y0f = floorf(py), x0f = floorf(px);
        float y1f = y0f + 1.0f, x1f = x0f + 1.0f;
        float wy = py - y0f, wx = px - x0f;
        bool vy0 = (y0f >= 0.0f) && (y0f <= (float)(HH - 1));
        bool vy1 = (y1f >= 0.0f) && (y1f <= (float)(HH - 1));
        bool vx0 = (x0f >= 0.0f) && (x0f <= (float)(WW - 1));
        bool vx1 = (x1f >= 0.0f) && (x1f <= (float)(WW - 1));
        int iy0 = (int)fminf(fmaxf(y0f, 0.0f), (float)(HH - 1));
        int iy1 = (int)fminf(fmaxf(y1f, 0.0f), (float)(HH - 1));
        int ix0 = (int)fminf(fmaxf(x0f, 0.0f), (float)(WW - 1));
        int ix1 = (int)fminf(fmaxf(x1f, 0.0f), (float)(WW - 1));
        float w00 = (1.0f - wy) * (1.0f - wx);
        float w01 = (1.0f - wy) * wx;
        float w10 = wy * (1.0f - wx);
        float w11 = wy * wx;
        #pragma unroll
        for (int c = 0; c < CIN; ++c) {
            const float* xc = xb + c * (HH * WW);
            float v00 = (vy0 && vx0) ? xc[iy0 * WW + ix0] : 0.0f;
            float v01 = (vy0 && vx1) ? xc[iy0 * WW + ix1] : 0.0f;
            float v10 = (vy1 && vx0) ? xc[iy1 * WW + ix0] : 0.0f;
            float v11 = (vy1 && vx1) ? xc[iy1 * WW + ix1] : 0.0f;
            samp[c * NDIR + n][g] = v00 * w00 + v01 * w01 + v10 * w10 + v11 * w11;
        }
    }
    __syncthreads();

    // ---- MFMA projection GEMM (proven in-register cvt path)
    const int lane = t & 63;
    const int wv   = t >> 6;           // 0..3; wave handles 6 N-tiles
    const int nrow = lane & 15;
    const int hi   = lane >> 4;

    bf16x8 afr[5];
    #pragma unroll
    for (int ks = 0; ks < 5; ++ks) {
        #pragma unroll
        for (int j = 0; j < 8; ++j) {
            int k = ks * 32 + hi * 8 + j;
            float v = (k < KK) ? samp[k][nrow] : 0.0f;
            afr[ks][j] = (__bf16)v;
        }
    }

    #pragma unroll
    for (int q = 0; q < 6; ++q) {
        int tile = wv * 6 + q;
        int e    = tile * 16 + nrow;
        const float* prow = pw + (size_t)e * KK;
        f32x4 acc = {0.0f, 0.0f, 0.0f, 0.0f};
        #pragma unroll
        for (int ks = 0; ks < 5; ++ks) {
            bf16x8 bfr;
            #pragma unroll
            for (int j = 0; j < 8; ++j) {
                int k = ks * 32 + hi * 8 + j;
                float v = (k < KK) ? prow[k] : 0.0f;
                bfr[j] = (__bf16)v;
            }
            acc = __builtin_amdgcn_mfma_f32_16x16x32_bf16(afr[ks], bfr, acc, 0, 0, 0);
        }
        float bias = pb[e];
        #pragma unroll
        for (int r = 0; r < 4; ++r) {
            out[(m0 + hi * 4 + r) * EE + e] = acc[r] + bias;
        }
    }
}

extern "C" void kernel_launch(void* const* d_in, const int* in_sizes, int n_in,
                              void* d_out, int out_size, void* d_ws, size_t ws_size,
                              hipStream_t stream) {
    const float* x  = (const float*)d_in[0];
    const float* mw = (const float*)d_in[1];
    const float* mb = (const float*)d_in[2];
    const float* pw = (const float*)d_in[3];
    const float* pb = (const float*)d_in[4];
    float* out = (float*)d_out;
    float* der = (float*)d_ws;                     // 65536 * 8 * 4 B = 2 MB

    const int B = in_sizes[0] / (CIN * HH * WW);   // 64
    const int NPATCH = B * 32 * 32;                // 65536

    params_kernel<<<NPATCH / TB1, TB1, 0, stream>>>(x, mw, mb, der);
    gather_gemm_kernel<<<B * 64, TB2, 0, stream>>>(x, der, pw, pb, out);
}

// Round 5
// 201.017 us; speedup vs baseline: 1.4288x; 1.2878x over previous
//
#include <hip/hip_runtime.h>
#include <math.h>

#define PP   7
#define NDIR 49
#define CIN  3
#define KK   147      // CIN * 49
#define KPAD 160      // bf16 B row stride: 5 k-steps of 32, zero-padded tail
#define EE   384
#define HH   224
#define WW   224
#define GG   16       // patches per block (main kernel)
#define TB1  256
#define TB2  256
#define SSTR 17       // samp LDS row stride (+1 pad: conflict-free A reads)

typedef __attribute__((ext_vector_type(8))) __bf16 bf16x8;
typedef __attribute__((ext_vector_type(4))) float  f32x4;

__device__ __forceinline__ float sigmoidf_(float v) {
    return 1.0f / (1.0f + expf(-v));
}

// ---- K0: pack proj_w (E,K) fp32 -> bf16 [E][KPAD], zero-padded (RNE like (__bf16) cast)
__global__ void pack_pw_kernel(const float* __restrict__ pw, unsigned short* __restrict__ pwB) {
    int idx = blockIdx.x * blockDim.x + threadIdx.x;
    if (idx < EE * KPAD) {
        int e = idx / KPAD;
        int k = idx - e * KPAD;
        float v = (k < KK) ? pw[e * KK + k] : 0.0f;
        __bf16 h = (__bf16)v;
        pwB[idx] = *(unsigned short*)&h;
    }
}

// ---- K1: per-patch metric conv + derived quantities -> der[p*8 + {0..4}]
__launch_bounds__(TB1)
__global__ void params_kernel(const float* __restrict__ x,
                              const float* __restrict__ mw,
                              const float* __restrict__ mb,
                              float* __restrict__ der) {
    __shared__ float mws[7 * KK];
    const int t = threadIdx.x;
    for (int i = t; i < 7 * KK; i += TB1) mws[i] = mw[i];
    __syncthreads();

    const int p   = blockIdx.x * TB1 + t;     // 0..65535
    const int b   = p >> 10;
    const int rem = p & 1023;
    const int hp  = rem >> 5;
    const int wp  = rem & 31;
    const float* xb = x + (size_t)b * (CIN * HH * WW) + (size_t)(hp * PP) * WW + wp * PP;

    float a0 = mb[0], a1 = mb[1], a2 = mb[2], a3 = mb[3], a4 = mb[4], a5 = mb[5], a6 = mb[6];
    #pragma unroll
    for (int c = 0; c < CIN; ++c) {
        #pragma unroll
        for (int i = 0; i < PP; ++i) {
            const float* row = xb + c * (HH * WW) + i * WW;
            float v[7];
            #pragma unroll
            for (int j = 0; j < PP; ++j) v[j] = row[j];
            const int kb = c * 49 + i * 7;
            #pragma unroll
            for (int j = 0; j < PP; ++j) {
                a0 = fmaf(v[j], mws[0 * KK + kb + j], a0);
                a1 = fmaf(v[j], mws[1 * KK + kb + j], a1);
                a2 = fmaf(v[j], mws[2 * KK + kb + j], a2);
                a3 = fmaf(v[j], mws[3 * KK + kb + j], a3);
                a4 = fmaf(v[j], mws[4 * KK + kb + j], a4);
                a5 = fmaf(v[j], mws[5 * KK + kb + j], a5);
                a6 = fmaf(v[j], mws[6 * KK + kb + j], a6);
            }
        }
    }

    float nrm = sqrtf(a0 * a0 + a1 * a1);
    float inv = 1.0f / fmaxf(nrm, 1e-12f);
    float v0 = a0 * inv, v1 = a1 * inv;
    float e0 = 2.0f * sigmoidf_(a2);
    float e1 = 2.0f * sigmoidf_(a3);
    float sc = 0.5f + 1.5f * sigmoidf_(a4);
    e0 *= sc; e1 *= sc;
    float M00 = e0 * v0 * v0 + e1 * v1 * v1;
    float M01 = (e0 - e1) * v0 * v1;
    float M11 = e0 * v1 * v1 + e1 * v0 * v0;
    float wn  = sqrtf(a5 * a5 + a6 * a6);
    float wsc = 0.5f * sigmoidf_(wn);

    float* dp = der + (size_t)p * 8;
    dp[0] = M00; dp[1] = M01; dp[2] = M11; dp[3] = a5 * wsc; dp[4] = a6 * wsc;
}

// ---- K2: gather + MFMA projection GEMM. 256 threads (4 waves), 16 patches.
__launch_bounds__(TB2)
__global__ void gather_gemm_kernel(const float* __restrict__ x,
                                   const float* __restrict__ derg,
                                   const unsigned short* __restrict__ pwB,
                                   const float* __restrict__ pb,
                                   float* __restrict__ out) {
    __shared__ float der_s[GG][5];
    __shared__ float dirs[NDIR][3];
    __shared__ float samp[KK][SSTR];   // fp32, row stride 17

    const int t   = threadIdx.x;
    const int blk = blockIdx.x;
    const int b   = blk >> 6;
    const int rem = blk & 63;
    const int hp  = rem >> 1;
    const int wp0 = (rem & 1) * GG;
    const size_t m0 = (size_t)blk * GG;

    const float* xb = x + (size_t)b * (CIN * HH * WW);

    // ---- init: derived params + direction table
    if (t < GG * 5) {
        int g = t / 5, f = t - g * 5;
        der_s[g][f] = derg[(m0 + g) * 8 + f];
    }
    if (t >= 64 && t < 64 + NDIR) {
        int n = t - 64;
        float u0, u1, s;
        if (n == 0)      { u0 = 1.0f; u1 = 0.0f; s = 0.0f; }
        else if (n < 9)  { float th = (float)(n - 1)  * 0.78539816339744831f; u0 = cosf(th); u1 = sinf(th); s = 0.33333334f; }
        else if (n < 25) { float th = (float)(n - 9)  * 0.39269908169872414f; u0 = cosf(th); u1 = sinf(th); s = 0.66666669f; }
        else             { float th = (float)(n - 25) * 0.26179938779914941f; u0 = cosf(th); u1 = sinf(th); s = 1.0f; }
        dirs[n][0] = u0; dirs[n][1] = u1; dirs[n][2] = s;
    }
    __syncthreads();

    // ---- positions + bilinear gather into samp[k][g] (proven R3/R4 math)
    for (int item = t; item < GG * NDIR; item += TB2) {
        int g = item / NDIR;
        int n = item - g * NDIR;
        float u0 = dirs[n][0], u1 = dirs[n][1], s = dirs[n][2];
        float M00 = der_s[g][0], M01 = der_s[g][1], M11 = der_s[g][2];
        float w0 = der_s[g][3], w1 = der_s[g][4];
        float quad  = u0 * u0 * M00 + 2.0f * u0 * u1 * M01 + u1 * u1 * M11;
        float drift = w0 * u0 + w1 * u1;
        float F = sqrtf(quad + 1e-6f) + drift;
        float r = s / (F + 1e-6f);
        float py = (float)(hp * PP + 3) + u1 * r;
        float px = (float)((wp0 + g) * PP + 3) + u0 * r;
        float y0f = floorf(py), x0f = floorf(px);
        float y1f = y0f + 1.0f, x1f = x0f + 1.0f;
        float wy = py - y0f, wx = px - x0f;
        bool vy0 = (y0f >= 0.0f) && (y0f <= (float)(HH - 1));
        bool vy1 = (y1f >= 0.0f) && (y1f <= (float)(HH - 1));
        bool vx0 = (x0f >= 0.0f) && (x0f <= (float)(WW - 1));
        bool vx1 = (x1f >= 0.0f) && (x1f <= (float)(WW - 1));
        int iy0 = (int)fminf(fmaxf(y0f, 0.0f), (float)(HH - 1));
        int iy1 = (int)fminf(fmaxf(y1f, 0.0f), (float)(HH - 1));
        int ix0 = (int)fminf(fmaxf(x0f, 0.0f), (float)(WW - 1));
        int ix1 = (int)fminf(fmaxf(x1f, 0.0f), (float)(WW - 1));
        float w00 = (1.0f - wy) * (1.0f - wx);
        float w01 = (1.0f - wy) * wx;
        float w10 = wy * (1.0f - wx);
        float w11 = wy * wx;
        #pragma unroll
        for (int c = 0; c < CIN; ++c) {
            const float* xc = xb + c * (HH * WW);
            float v00 = (vy0 && vx0) ? xc[iy0 * WW + ix0] : 0.0f;
            float v01 = (vy0 && vx1) ? xc[iy0 * WW + ix1] : 0.0f;
            float v10 = (vy1 && vx0) ? xc[iy1 * WW + ix0] : 0.0f;
            float v11 = (vy1 && vx1) ? xc[iy1 * WW + ix1] : 0.0f;
            samp[c * NDIR + n][g] = v00 * w00 + v01 * w01 + v10 * w10 + v11 * w11;
        }
    }
    __syncthreads();

    // ---- MFMA projection GEMM; A: fp32 LDS + in-register cvt (proven),
    //      B: bf16x8 vector loads from packed pwB (16 B/lane, 1 instr per tile/ks)
    const int lane = t & 63;
    const int wv   = t >> 6;           // 0..3; wave handles 6 N-tiles
    const int nrow = lane & 15;
    const int hi   = lane >> 4;

    bf16x8 afr[5];
    #pragma unroll
    for (int ks = 0; ks < 5; ++ks) {
        #pragma unroll
        for (int j = 0; j < 8; ++j) {
            int k = ks * 32 + hi * 8 + j;
            float v = (k < KK) ? samp[k][nrow] : 0.0f;
            afr[ks][j] = (__bf16)v;
        }
    }

    #pragma unroll
    for (int q = 0; q < 6; ++q) {
        int tile = wv * 6 + q;
        int e    = tile * 16 + nrow;
        const unsigned short* brow = pwB + (size_t)e * KPAD + hi * 8;
        f32x4 acc = {0.0f, 0.0f, 0.0f, 0.0f};
        #pragma unroll
        for (int ks = 0; ks < 5; ++ks) {
            bf16x8 bfr = *(const bf16x8*)&brow[ks * 32];
            acc = __builtin_amdgcn_mfma_f32_16x16x32_bf16(afr[ks], bfr, acc, 0, 0, 0);
        }
        float bias = pb[e];
        #pragma unroll
        for (int r = 0; r < 4; ++r) {
            out[(m0 + hi * 4 + r) * EE + e] = acc[r] + bias;
        }
    }
}

extern "C" void kernel_launch(void* const* d_in, const int* in_sizes, int n_in,
                              void* d_out, int out_size, void* d_ws, size_t ws_size,
                              hipStream_t stream) {
    const float* x  = (const float*)d_in[0];
    const float* mw = (const float*)d_in[1];
    const float* mb = (const float*)d_in[2];
    const float* pw = (const float*)d_in[3];
    const float* pb = (const float*)d_in[4];
    float* out = (float*)d_out;
    float* der = (float*)d_ws;                              // 65536*8*4 B = 2 MB
    unsigned short* pwB = (unsigned short*)((char*)d_ws + (size_t)65536 * 8 * 4);  // 120 KB

    const int B = in_sizes[0] / (CIN * HH * WW);   // 64
    const int NPATCH = B * 32 * 32;                // 65536

    pack_pw_kernel<<<(EE * KPAD + 255) / 256, 256, 0, stream>>>(pw, pwB);
    params_kernel<<<NPATCH / TB1, TB1, 0, stream>>>(x, mw, mb, der);
    gather_gemm_kernel<<<B * 64, TB2, 0, stream>>>(x, der, pwB, pb, out);
}